// Round 10
// baseline (529.205 us; speedup 1.0000x reference)
//
#include <hip/hip_runtime.h>
#include <hip/hip_bf16.h>
#include <hip/hip_fp16.h>

#define NN 50000
#define NE 1600000
#define DIM 128
#define NU 10000
#define NB 128           // histogram/scatter chunks
#define SLICE_W 12500    // NN/4 packed-uint8 words per slice
#define NE4 (NE / 4)
#define CHUNK4 (NE4 / NB)  // 3125 int4 per block
#define NSC 49           // scan blocks: ceil(NN/1024)
#define TILE_N 12500     // src-tile size for L2-resident aggregate (3.2 MB fp16)

// Fused per-chunk packed-uint8 histograms: blocks [0,NB) -> dst, [NB,2NB) -> src
__global__ __launch_bounds__(512) void k_hist(const int4* __restrict__ src4,
                                              const int4* __restrict__ dst4,
                                              unsigned int* __restrict__ histD,
                                              unsigned int* __restrict__ histS) {
    __shared__ unsigned int lh[SLICE_W];   // 50 KB
    for (int i = threadIdx.x; i < SLICE_W; i += 512) lh[i] = 0u;
    __syncthreads();
    int b = blockIdx.x & (NB - 1);
    const int4* idx4 = (blockIdx.x < NB) ? dst4 : src4;
    unsigned int* out = ((blockIdx.x < NB) ? histD : histS) + (size_t)b * SLICE_W;
    int beg = b * CHUNK4, end = beg + CHUNK4;
    for (int i = beg + threadIdx.x; i < end; i += 512) {
        int4 v = idx4[i];
        atomicAdd(&lh[v.x >> 2], 1u << ((v.x & 3) * 8));
        atomicAdd(&lh[v.y >> 2], 1u << ((v.y & 3) * 8));
        atomicAdd(&lh[v.z >> 2], 1u << ((v.z & 3) * 8));
        atomicAdd(&lh[v.w >> 2], 1u << ((v.w & 3) * 8));
    }
    __syncthreads();
    for (int i = threadIdx.x; i < SLICE_W; i += 512) out[i] = lh[i];
}

// Sum NB slices per node; emit din, cs, cd, per-block degree partials
__global__ __launch_bounds__(256) void k_reduce_norms(const unsigned int* __restrict__ histD,
                                                      const unsigned int* __restrict__ histS,
                                                      int* __restrict__ din,
                                                      float* __restrict__ cs, float* __restrict__ cd,
                                                      int* __restrict__ partials) {
    __shared__ int red[256];
    int wi = blockIdx.x * blockDim.x + threadIdx.x;
    unsigned int d0 = 0, d1 = 0, d2 = 0, d3 = 0, s0 = 0, s1 = 0, s2 = 0, s3 = 0;
    if (wi < SLICE_W) {
        for (int b = 0; b < NB; ++b) {
            unsigned int wd = histD[(size_t)b * SLICE_W + wi];
            unsigned int ws = histS[(size_t)b * SLICE_W + wi];
            d0 += wd & 0xFFu; d1 += (wd >> 8) & 0xFFu; d2 += (wd >> 16) & 0xFFu; d3 += wd >> 24;
            s0 += ws & 0xFFu; s1 += (ws >> 8) & 0xFFu; s2 += (ws >> 16) & 0xFFu; s3 += ws >> 24;
        }
        int n = wi * 4;
        *(int4*)&din[n] = make_int4(d0, d1, d2, d3);
        float4 vcd, vcs;
        vcd.x = rsqrtf(fmaxf((float)d0, 1.f)); vcd.y = rsqrtf(fmaxf((float)d1, 1.f));
        vcd.z = rsqrtf(fmaxf((float)d2, 1.f)); vcd.w = rsqrtf(fmaxf((float)d3, 1.f));
        vcs.x = rsqrtf(fmaxf((float)s0, 1.f)); vcs.y = rsqrtf(fmaxf((float)s1, 1.f));
        vcs.z = rsqrtf(fmaxf((float)s2, 1.f)); vcs.w = rsqrtf(fmaxf((float)s3, 1.f));
        *(float4*)&cd[n] = vcd;
        *(float4*)&cs[n] = vcs;
    }
    red[threadIdx.x] = (int)(d0 + d1 + d2 + d3);
    __syncthreads();
    for (int off = 128; off > 0; off >>= 1) {
        if (threadIdx.x < off) red[threadIdx.x] += red[threadIdx.x + off];
        __syncthreads();
    }
    if (threadIdx.x == 0) partials[blockIdx.x] = red[0];
}

__global__ __launch_bounds__(64) void k_scan2(const int* __restrict__ partials,
                                              int* __restrict__ bases) {
    int lane = threadIdx.x;
    int v = (lane < NSC) ? partials[lane] : 0;
    int s = v;
    for (int off = 1; off < 64; off <<= 1) {
        int n = __shfl_up(s, off);
        if (lane >= off) s += n;
    }
    if (lane < NSC) bases[lane] = s - v;
}

__global__ __launch_bounds__(256) void k_scan3(const int* __restrict__ din,
                                               const int* __restrict__ bases,
                                               int* __restrict__ offs) {
    __shared__ int part[256];
    int t = threadIdx.x;
    int n0 = blockIdx.x * 1024 + t * 4;
    int4 d = make_int4(0, 0, 0, 0);
    if (n0 < NN) d = *(const int4*)&din[n0];
    int tsum = d.x + d.y + d.z + d.w;
    part[t] = tsum;
    __syncthreads();
    for (int off = 1; off < 256; off <<= 1) {
        int v = (t >= off) ? part[t - off] : 0;
        __syncthreads();
        part[t] += v;
        __syncthreads();
    }
    if (n0 < NN) {
        int o = bases[blockIdx.x] + part[t] - tsum;
        *(int4*)&offs[n0] = make_int4(o, o + d.x, o + d.x + d.y, o + d.x + d.y + d.z);
    }
}

// rel8[b][n] = sum over b' < b of histD[b'][n]  (<= deg_in, fits uint8)
__global__ __launch_bounds__(256) void k_blockbase(const unsigned int* __restrict__ histD,
                                                   unsigned char* __restrict__ rel8) {
    int n = blockIdx.x * blockDim.x + threadIdx.x;
    if (n >= NN) return;
    int wi = n >> 2, sh = (n & 3) * 8;
    unsigned int run = 0;
    for (int b = 0; b < NB; ++b) {
        rel8[(size_t)b * NN + n] = (unsigned char)run;
        run += (histD[(size_t)b * SLICE_W + wi] >> sh) & 0xFFu;
    }
}

// Atomic-free CSC scatter: local position from LDS packed-byte cursor
__global__ __launch_bounds__(512) void k_scatter2(const int4* __restrict__ src4,
                                                  const int4* __restrict__ dst4,
                                                  const int* __restrict__ offs,
                                                  const unsigned char* __restrict__ rel8,
                                                  int* __restrict__ csc) {
    __shared__ unsigned int lc[SLICE_W];   // 50 KB
    for (int i = threadIdx.x; i < SLICE_W; i += 512) lc[i] = 0u;
    __syncthreads();
    int b = blockIdx.x;
    const unsigned char* rel = rel8 + (size_t)b * NN;
    int beg = b * CHUNK4, end = beg + CHUNK4;
    for (int i = beg + threadIdx.x; i < end; i += 512) {
        int4 s = src4[i];
        int4 d = dst4[i];
#pragma unroll
        for (int j = 0; j < 4; ++j) {
            int dd = (j == 0) ? d.x : (j == 1) ? d.y : (j == 2) ? d.z : d.w;
            int ss = (j == 0) ? s.x : (j == 1) ? s.y : (j == 2) ? s.z : s.w;
            int sh = (dd & 3) * 8;
            unsigned int old = atomicAdd(&lc[dd >> 2], 1u << sh);
            int local = (old >> sh) & 0xFF;
            csc[offs[dd] + rel[dd] + local] = ss;
        }
    }
}

// Y[r][:] = fp16((X[r][:] @ W) * cs[r]) ; 4 rows per wave (R4-benched version, no spills)
__global__ __launch_bounds__(256) void k_matmul_cs(const float* __restrict__ X,
                                                   const float* __restrict__ W,
                                                   const float* __restrict__ cs,
                                                   __half* __restrict__ Y, int nrows) {
    __shared__ float sW[DIM * DIM];   // 64 KB
    __shared__ float sX[16][DIM];     //  8 KB
    for (int i = threadIdx.x * 4; i < DIM * DIM; i += 256 * 4)
        *(float4*)&sW[i] = *(const float4*)&W[i];
    int rl = threadIdx.x >> 6;
    int c = (threadIdx.x & 63) * 2;
    int ngroups = (nrows + 15) >> 4;
    for (int g = blockIdx.x; g < ngroups; g += gridDim.x) {
        __syncthreads();
        {
            int row = threadIdx.x >> 4;
            int col = (threadIdx.x & 15) * 8;
            int rr = min(g * 16 + row, nrows - 1);
            const float* xp = X + (size_t)rr * DIM + col;
            *(float4*)&sX[row][col] = *(const float4*)xp;
            *(float4*)&sX[row][col + 4] = *(const float4*)(xp + 4);
        }
        __syncthreads();
        float acc[4][2] = {};
#pragma unroll 4
        for (int k = 0; k < DIM; ++k) {
            float2 w = *(const float2*)&sW[k * DIM + c];
            float x0 = sX[rl * 4 + 0][k];
            float x1 = sX[rl * 4 + 1][k];
            float x2 = sX[rl * 4 + 2][k];
            float x3 = sX[rl * 4 + 3][k];
            acc[0][0] = fmaf(x0, w.x, acc[0][0]); acc[0][1] = fmaf(x0, w.y, acc[0][1]);
            acc[1][0] = fmaf(x1, w.x, acc[1][0]); acc[1][1] = fmaf(x1, w.y, acc[1][1]);
            acc[2][0] = fmaf(x2, w.x, acc[2][0]); acc[2][1] = fmaf(x2, w.y, acc[2][1]);
            acc[3][0] = fmaf(x3, w.x, acc[3][0]); acc[3][1] = fmaf(x3, w.y, acc[3][1]);
        }
#pragma unroll
        for (int j = 0; j < 4; ++j) {
            int r = g * 16 + rl * 4 + j;
            if (r < nrows) {
                float s = cs[r];
                __half2 hv = __float22half2_rn(make_float2(acc[j][0] * s, acc[j][1] * s));
                *(__half2*)&Y[(size_t)r * DIM + c] = hv;
            }
        }
    }
}

// Full-row aggregate with src-tiling: 4 passes over the dst's index list,
// each gathering only rows in a 3.2MB tile (fits per-XCD L2).
// 32 lanes x 8B cover the 256B row; wave-halves take even/odd edge slots.
__global__ __launch_bounds__(256) void k_aggregate(const __half* __restrict__ hs,
                                                   const int* __restrict__ csc,
                                                   const int* __restrict__ offs,
                                                   const int* __restrict__ din,
                                                   const float* __restrict__ cd,
                                                   const float* __restrict__ bias,
                                                   float* __restrict__ out) {
    int wid = threadIdx.x >> 6;
    int lane = threadIdx.x & 63;
    int h = lane >> 5;        // edge-slot parity
    int l = lane & 31;        // dim group: dims l*4 .. l*4+3
    int d = blockIdx.x * 4 + wid;   // NN % 4 == 0
    int beg = offs[d];
    int end = beg + din[d];
    const __half* base = hs + l * 4;
    float a0 = 0.f, a1 = 0.f, a2 = 0.f, a3 = 0.f;
    float b0 = 0.f, b1 = 0.f, b2 = 0.f, b3 = 0.f;
#pragma unroll 1
    for (int t = 0; t < 4; ++t) {
        int lo = t * TILE_N;
        for (int i = beg + h; i < end; i += 4) {
            int s0 = csc[i];
            int s1 = (i + 2 < end) ? csc[i + 2] : -1;
            bool m0 = (unsigned)(s0 - lo) < (unsigned)TILE_N;
            bool m1 = (unsigned)(s1 - lo) < (unsigned)TILE_N;
            if (m0) {
                short4 v = *(const short4*)(base + (size_t)s0 * DIM);
                float2 x0 = __half22float2(*(const __half2*)&v.x);
                float2 x1 = __half22float2(*(const __half2*)&v.z);
                a0 += x0.x; a1 += x0.y; a2 += x1.x; a3 += x1.y;
            }
            if (m1) {
                short4 v = *(const short4*)(base + (size_t)s1 * DIM);
                float2 y0 = __half22float2(*(const __half2*)&v.x);
                float2 y1 = __half22float2(*(const __half2*)&v.z);
                b0 += y0.x; b1 += y0.y; b2 += y1.x; b3 += y1.y;
            }
        }
    }
    a0 += b0; a1 += b1; a2 += b2; a3 += b3;
    a0 += __shfl(a0, lane ^ 32);
    a1 += __shfl(a1, lane ^ 32);
    a2 += __shfl(a2, lane ^ 32);
    a3 += __shfl(a3, lane ^ 32);
    if (h == 0) {
        float c = cd[d];
        float4 bv = *(const float4*)&bias[l * 4];
        float4 o;
        o.x = fmaxf(fmaf(a0, c, bv.x), 0.f);
        o.y = fmaxf(fmaf(a1, c, bv.y), 0.f);
        o.z = fmaxf(fmaf(a2, c, bv.z), 0.f);
        o.w = fmaxf(fmaf(a3, c, bv.w), 0.f);
        *(float4*)&out[(size_t)d * DIM + l * 4] = o;
    }
}

// R[u][:] = tanh(h[users[u]] @ Ws1 + bs1) @ Ws2 + bs2
__global__ __launch_bounds__(256) void k_sr_head(const float* __restrict__ h,
                                                 const int* __restrict__ users,
                                                 const float* __restrict__ Ws1,
                                                 const float* __restrict__ bs1,
                                                 const float* __restrict__ Ws2,
                                                 const float* __restrict__ bs2,
                                                 float* __restrict__ R, int nu) {
    __shared__ float sW1[DIM * 64];
    __shared__ float sW2[64 * 64];
    __shared__ float sU[4][DIM];
    __shared__ float sT[4][64];
    for (int i = threadIdx.x * 4; i < DIM * 64; i += 256 * 4)
        *(float4*)&sW1[i] = *(const float4*)&Ws1[i];
    for (int i = threadIdx.x * 4; i < 64 * 64; i += 256 * 4)
        *(float4*)&sW2[i] = *(const float4*)&Ws2[i];
    int ul = threadIdx.x >> 6;
    int c = threadIdx.x & 63;
    for (int base = blockIdx.x * 4; base < nu; base += gridDim.x * 4) {
        int u = base + ul;
        __syncthreads();
        if (u < nu) {
            int node = users[u];
            *(float2*)&sU[ul][c * 2] = *(const float2*)&h[(size_t)node * DIM + c * 2];
        }
        __syncthreads();
        float t = 0.f;
        if (u < nu) {
            float acc = bs1[c];
#pragma unroll 8
            for (int k = 0; k < DIM; ++k) acc = fmaf(sU[ul][k], sW1[k * 64 + c], acc);
            t = tanhf(acc);
        }
        sT[ul][c] = t;
        __syncthreads();
        if (u < nu) {
            float acc = bs2[c];
#pragma unroll 8
            for (int k = 0; k < 64; ++k) acc = fmaf(sT[ul][k], sW2[k * 64 + c], acc);
            R[(size_t)u * 64 + c] = acc;
        }
    }
}

extern "C" void kernel_launch(void* const* d_in, const int* in_sizes, int n_in,
                              void* d_out, int out_size, void* d_ws, size_t ws_size,
                              hipStream_t stream) {
    const float* features = (const float*)d_in[0];
    const float* W0  = (const float*)d_in[1];
    const float* b0  = (const float*)d_in[2];
    const float* W1  = (const float*)d_in[3];
    const float* b1  = (const float*)d_in[4];
    const float* Ws1 = (const float*)d_in[5];
    const float* bs1 = (const float*)d_in[6];
    const float* Ws2 = (const float*)d_in[7];
    const float* bs2 = (const float*)d_in[8];
    const int* src   = (const int*)d_in[9];
    const int* dst   = (const int*)d_in[10];
    const int* users = (const int*)d_in[11];

    float* R = (float*)d_out;
    float* H = (float*)d_out + (size_t)NU * 64;

    char* ws = (char*)d_ws;
    // hist buffers overlay hsA: dead before matmul1 writes hsA
    __half* hsA  = (__half*)(ws + 0);                      // 12.8 MB
    unsigned int* histD = (unsigned int*)(ws + 0);         //  6.4 MB (128 x 50000B)
    unsigned int* histS = (unsigned int*)(ws + 6400000);   //  6.4 MB
    int* csc     = (int*)(ws + 12800000);                  //  6.4 MB
    unsigned char* rel8 = (unsigned char*)(ws + 19200000); //  6.4 MB
    int*   din   = (int*)  (ws + 25600000);
    float* cs    = (float*)(ws + 25800000);
    float* cd    = (float*)(ws + 26000000);
    int*   offs  = (int*)  (ws + 26200000);
    int*   partials = (int*)(ws + 26400000);
    int*   bases    = (int*)(ws + 26401024);               // end ~26.5 MB

    k_hist<<<2 * NB, 512, 0, stream>>>((const int4*)src, (const int4*)dst, histD, histS);
    k_reduce_norms<<<NSC, 256, 0, stream>>>(histD, histS, din, cs, cd, partials);
    k_scan2<<<1, 64, 0, stream>>>(partials, bases);
    k_scan3<<<NSC, 256, 0, stream>>>(din, bases, offs);
    k_blockbase<<<(NN + 255) / 256, 256, 0, stream>>>(histD, rel8);
    k_scatter2<<<NB, 512, 0, stream>>>((const int4*)src, (const int4*)dst, offs, rel8, csc);

    // layer 1
    k_matmul_cs<<<1024, 256, 0, stream>>>(features, W0, cs, hsA, NN);
    k_aggregate<<<12500, 256, 0, stream>>>(hsA, csc, offs, din, cd, b0, H);

    // layer 2
    k_matmul_cs<<<1024, 256, 0, stream>>>(H, W1, cs, hsA, NN);
    k_aggregate<<<12500, 256, 0, stream>>>(hsA, csc, offs, din, cd, b1, H);

    // SR head
    k_sr_head<<<2500, 256, 0, stream>>>(H, users, Ws1, bs1, Ws2, bs2, R, NU);
}

// Round 11
// 309.290 us; speedup vs baseline: 1.7110x; 1.7110x over previous
//
#include <hip/hip_runtime.h>
#include <hip/hip_bf16.h>
#include <hip/hip_fp16.h>

#define NN 50000
#define NE 1600000
#define DIM 128
#define NU 10000
#define NB 128           // histogram/scatter chunks
#define SLICE_W 12500    // NN/4 packed-uint8 words per slice
#define NE4 (NE / 4)
#define CHUNK4 (NE4 / NB)  // 3125 int4 per block
#define NSC 49           // scan blocks: ceil(NN/1024)

// Fused per-chunk packed-uint8 histograms: blocks [0,NB) -> dst, [NB,2NB) -> src
__global__ __launch_bounds__(512) void k_hist(const int4* __restrict__ src4,
                                              const int4* __restrict__ dst4,
                                              unsigned int* __restrict__ histD,
                                              unsigned int* __restrict__ histS) {
    __shared__ unsigned int lh[SLICE_W];   // 50 KB
    for (int i = threadIdx.x; i < SLICE_W; i += 512) lh[i] = 0u;
    __syncthreads();
    int b = blockIdx.x & (NB - 1);
    const int4* idx4 = (blockIdx.x < NB) ? dst4 : src4;
    unsigned int* out = ((blockIdx.x < NB) ? histD : histS) + (size_t)b * SLICE_W;
    int beg = b * CHUNK4, end = beg + CHUNK4;
    for (int i = beg + threadIdx.x; i < end; i += 512) {
        int4 v = idx4[i];
        atomicAdd(&lh[v.x >> 2], 1u << ((v.x & 3) * 8));
        atomicAdd(&lh[v.y >> 2], 1u << ((v.y & 3) * 8));
        atomicAdd(&lh[v.z >> 2], 1u << ((v.z & 3) * 8));
        atomicAdd(&lh[v.w >> 2], 1u << ((v.w & 3) * 8));
    }
    __syncthreads();
    for (int i = threadIdx.x; i < SLICE_W; i += 512) out[i] = lh[i];
}

// Sum NB slices per node; emit din, cs, cd, per-block degree partials
__global__ __launch_bounds__(256) void k_reduce_norms(const unsigned int* __restrict__ histD,
                                                      const unsigned int* __restrict__ histS,
                                                      int* __restrict__ din,
                                                      float* __restrict__ cs, float* __restrict__ cd,
                                                      int* __restrict__ partials) {
    __shared__ int red[256];
    int wi = blockIdx.x * blockDim.x + threadIdx.x;
    unsigned int d0 = 0, d1 = 0, d2 = 0, d3 = 0, s0 = 0, s1 = 0, s2 = 0, s3 = 0;
    if (wi < SLICE_W) {
        for (int b = 0; b < NB; ++b) {
            unsigned int wd = histD[(size_t)b * SLICE_W + wi];
            unsigned int ws = histS[(size_t)b * SLICE_W + wi];
            d0 += wd & 0xFFu; d1 += (wd >> 8) & 0xFFu; d2 += (wd >> 16) & 0xFFu; d3 += wd >> 24;
            s0 += ws & 0xFFu; s1 += (ws >> 8) & 0xFFu; s2 += (ws >> 16) & 0xFFu; s3 += ws >> 24;
        }
        int n = wi * 4;
        *(int4*)&din[n] = make_int4(d0, d1, d2, d3);
        float4 vcd, vcs;
        vcd.x = rsqrtf(fmaxf((float)d0, 1.f)); vcd.y = rsqrtf(fmaxf((float)d1, 1.f));
        vcd.z = rsqrtf(fmaxf((float)d2, 1.f)); vcd.w = rsqrtf(fmaxf((float)d3, 1.f));
        vcs.x = rsqrtf(fmaxf((float)s0, 1.f)); vcs.y = rsqrtf(fmaxf((float)s1, 1.f));
        vcs.z = rsqrtf(fmaxf((float)s2, 1.f)); vcs.w = rsqrtf(fmaxf((float)s3, 1.f));
        *(float4*)&cd[n] = vcd;
        *(float4*)&cs[n] = vcs;
    }
    red[threadIdx.x] = (int)(d0 + d1 + d2 + d3);
    __syncthreads();
    for (int off = 128; off > 0; off >>= 1) {
        if (threadIdx.x < off) red[threadIdx.x] += red[threadIdx.x + off];
        __syncthreads();
    }
    if (threadIdx.x == 0) partials[blockIdx.x] = red[0];
}

__global__ __launch_bounds__(64) void k_scan2(const int* __restrict__ partials,
                                              int* __restrict__ bases) {
    int lane = threadIdx.x;
    int v = (lane < NSC) ? partials[lane] : 0;
    int s = v;
    for (int off = 1; off < 64; off <<= 1) {
        int n = __shfl_up(s, off);
        if (lane >= off) s += n;
    }
    if (lane < NSC) bases[lane] = s - v;
}

__global__ __launch_bounds__(256) void k_scan3(const int* __restrict__ din,
                                               const int* __restrict__ bases,
                                               int* __restrict__ offs) {
    __shared__ int part[256];
    int t = threadIdx.x;
    int n0 = blockIdx.x * 1024 + t * 4;
    int4 d = make_int4(0, 0, 0, 0);
    if (n0 < NN) d = *(const int4*)&din[n0];
    int tsum = d.x + d.y + d.z + d.w;
    part[t] = tsum;
    __syncthreads();
    for (int off = 1; off < 256; off <<= 1) {
        int v = (t >= off) ? part[t - off] : 0;
        __syncthreads();
        part[t] += v;
        __syncthreads();
    }
    if (n0 < NN) {
        int o = bases[blockIdx.x] + part[t] - tsum;
        *(int4*)&offs[n0] = make_int4(o, o + d.x, o + d.x + d.y, o + d.x + d.y + d.z);
    }
}

// rel8[b][n] = sum over b' < b of histD[b'][n]  (<= deg_in, fits uint8)
__global__ __launch_bounds__(256) void k_blockbase(const unsigned int* __restrict__ histD,
                                                   unsigned char* __restrict__ rel8) {
    int n = blockIdx.x * blockDim.x + threadIdx.x;
    if (n >= NN) return;
    int wi = n >> 2, sh = (n & 3) * 8;
    unsigned int run = 0;
    for (int b = 0; b < NB; ++b) {
        rel8[(size_t)b * NN + n] = (unsigned char)run;
        run += (histD[(size_t)b * SLICE_W + wi] >> sh) & 0xFFu;
    }
}

// Atomic-free CSC scatter: local position from LDS packed-byte cursor
__global__ __launch_bounds__(512) void k_scatter2(const int4* __restrict__ src4,
                                                  const int4* __restrict__ dst4,
                                                  const int* __restrict__ offs,
                                                  const unsigned char* __restrict__ rel8,
                                                  int* __restrict__ csc) {
    __shared__ unsigned int lc[SLICE_W];   // 50 KB
    for (int i = threadIdx.x; i < SLICE_W; i += 512) lc[i] = 0u;
    __syncthreads();
    int b = blockIdx.x;
    const unsigned char* rel = rel8 + (size_t)b * NN;
    int beg = b * CHUNK4, end = beg + CHUNK4;
    for (int i = beg + threadIdx.x; i < end; i += 512) {
        int4 s = src4[i];
        int4 d = dst4[i];
#pragma unroll
        for (int j = 0; j < 4; ++j) {
            int dd = (j == 0) ? d.x : (j == 1) ? d.y : (j == 2) ? d.z : d.w;
            int ss = (j == 0) ? s.x : (j == 1) ? s.y : (j == 2) ? s.z : s.w;
            int sh = (dd & 3) * 8;
            unsigned int old = atomicAdd(&lc[dd >> 2], 1u << sh);
            int local = (old >> sh) & 0xFF;
            csc[offs[dd] + rel[dd] + local] = ss;
        }
    }
}

// Y[r][:] = fp16((X[r][:] @ W) * cs[r]) ; 4 rows per wave (R4-benched version, no spills)
__global__ __launch_bounds__(256) void k_matmul_cs(const float* __restrict__ X,
                                                   const float* __restrict__ W,
                                                   const float* __restrict__ cs,
                                                   __half* __restrict__ Y, int nrows) {
    __shared__ float sW[DIM * DIM];   // 64 KB
    __shared__ float sX[16][DIM];     //  8 KB
    for (int i = threadIdx.x * 4; i < DIM * DIM; i += 256 * 4)
        *(float4*)&sW[i] = *(const float4*)&W[i];
    int rl = threadIdx.x >> 6;
    int c = (threadIdx.x & 63) * 2;
    int ngroups = (nrows + 15) >> 4;
    for (int g = blockIdx.x; g < ngroups; g += gridDim.x) {
        __syncthreads();
        {
            int row = threadIdx.x >> 4;
            int col = (threadIdx.x & 15) * 8;
            int rr = min(g * 16 + row, nrows - 1);
            const float* xp = X + (size_t)rr * DIM + col;
            *(float4*)&sX[row][col] = *(const float4*)xp;
            *(float4*)&sX[row][col + 4] = *(const float4*)(xp + 4);
        }
        __syncthreads();
        float acc[4][2] = {};
#pragma unroll 4
        for (int k = 0; k < DIM; ++k) {
            float2 w = *(const float2*)&sW[k * DIM + c];
            float x0 = sX[rl * 4 + 0][k];
            float x1 = sX[rl * 4 + 1][k];
            float x2 = sX[rl * 4 + 2][k];
            float x3 = sX[rl * 4 + 3][k];
            acc[0][0] = fmaf(x0, w.x, acc[0][0]); acc[0][1] = fmaf(x0, w.y, acc[0][1]);
            acc[1][0] = fmaf(x1, w.x, acc[1][0]); acc[1][1] = fmaf(x1, w.y, acc[1][1]);
            acc[2][0] = fmaf(x2, w.x, acc[2][0]); acc[2][1] = fmaf(x2, w.y, acc[2][1]);
            acc[3][0] = fmaf(x3, w.x, acc[3][0]); acc[3][1] = fmaf(x3, w.y, acc[3][1]);
        }
#pragma unroll
        for (int j = 0; j < 4; ++j) {
            int r = g * 16 + rl * 4 + j;
            if (r < nrows) {
                float s = cs[r];
                __half2 hv = __float22half2_rn(make_float2(acc[j][0] * s, acc[j][1] * s));
                *(__half2*)&Y[(size_t)r * DIM + c] = hv;
            }
        }
    }
}

// Full-row aggregate, 4-deep edge unroll: 32 lanes x 8B cover the 256B row,
// wave-halves take even/odd edge slots, each half keeps 4 gathers in flight.
__global__ __launch_bounds__(256) void k_aggregate(const __half* __restrict__ hs,
                                                   const int* __restrict__ csc,
                                                   const int* __restrict__ offs,
                                                   const int* __restrict__ din,
                                                   const float* __restrict__ cd,
                                                   const float* __restrict__ bias,
                                                   float* __restrict__ out) {
    int wid = threadIdx.x >> 6;
    int lane = threadIdx.x & 63;
    int h = lane >> 5;        // edge-slot parity
    int l = lane & 31;        // dim group: dims l*4 .. l*4+3
    int d = blockIdx.x * 4 + wid;   // NN % 4 == 0
    int beg = offs[d];
    int end = beg + din[d];
    const __half* base = hs + l * 4;
    float a0 = 0.f, a1 = 0.f, a2 = 0.f, a3 = 0.f;
    float b0 = 0.f, b1 = 0.f, b2 = 0.f, b3 = 0.f;
    float c0 = 0.f, c1 = 0.f, c2 = 0.f, c3 = 0.f;
    float e0 = 0.f, e1 = 0.f, e2 = 0.f, e3 = 0.f;
    int i = beg + h;
    for (; i + 6 < end; i += 8) {
        int s0 = csc[i], s1 = csc[i + 2], s2 = csc[i + 4], s3 = csc[i + 6];
        short4 v0 = *(const short4*)(base + (size_t)s0 * DIM);
        short4 v1 = *(const short4*)(base + (size_t)s1 * DIM);
        short4 v2 = *(const short4*)(base + (size_t)s2 * DIM);
        short4 v3 = *(const short4*)(base + (size_t)s3 * DIM);
        float2 x0 = __half22float2(*(const __half2*)&v0.x);
        float2 x1 = __half22float2(*(const __half2*)&v0.z);
        float2 y0 = __half22float2(*(const __half2*)&v1.x);
        float2 y1 = __half22float2(*(const __half2*)&v1.z);
        float2 z0 = __half22float2(*(const __half2*)&v2.x);
        float2 z1 = __half22float2(*(const __half2*)&v2.z);
        float2 w0 = __half22float2(*(const __half2*)&v3.x);
        float2 w1 = __half22float2(*(const __half2*)&v3.z);
        a0 += x0.x; a1 += x0.y; a2 += x1.x; a3 += x1.y;
        b0 += y0.x; b1 += y0.y; b2 += y1.x; b3 += y1.y;
        c0 += z0.x; c1 += z0.y; c2 += z1.x; c3 += z1.y;
        e0 += w0.x; e1 += w0.y; e2 += w1.x; e3 += w1.y;
    }
    for (; i < end; i += 2) {
        int s = csc[i];
        short4 v = *(const short4*)(base + (size_t)s * DIM);
        float2 x0 = __half22float2(*(const __half2*)&v.x);
        float2 x1 = __half22float2(*(const __half2*)&v.z);
        a0 += x0.x; a1 += x0.y; a2 += x1.x; a3 += x1.y;
    }
    a0 += b0 + c0 + e0; a1 += b1 + c1 + e1;
    a2 += b2 + c2 + e2; a3 += b3 + c3 + e3;
    a0 += __shfl(a0, lane ^ 32);
    a1 += __shfl(a1, lane ^ 32);
    a2 += __shfl(a2, lane ^ 32);
    a3 += __shfl(a3, lane ^ 32);
    if (h == 0) {
        float c = cd[d];
        float4 bv = *(const float4*)&bias[l * 4];
        float4 o;
        o.x = fmaxf(fmaf(a0, c, bv.x), 0.f);
        o.y = fmaxf(fmaf(a1, c, bv.y), 0.f);
        o.z = fmaxf(fmaf(a2, c, bv.z), 0.f);
        o.w = fmaxf(fmaf(a3, c, bv.w), 0.f);
        *(float4*)&out[(size_t)d * DIM + l * 4] = o;
    }
}

// R[u][:] = tanh(h[users[u]] @ Ws1 + bs1) @ Ws2 + bs2
__global__ __launch_bounds__(256) void k_sr_head(const float* __restrict__ h,
                                                 const int* __restrict__ users,
                                                 const float* __restrict__ Ws1,
                                                 const float* __restrict__ bs1,
                                                 const float* __restrict__ Ws2,
                                                 const float* __restrict__ bs2,
                                                 float* __restrict__ R, int nu) {
    __shared__ float sW1[DIM * 64];
    __shared__ float sW2[64 * 64];
    __shared__ float sU[4][DIM];
    __shared__ float sT[4][64];
    for (int i = threadIdx.x * 4; i < DIM * 64; i += 256 * 4)
        *(float4*)&sW1[i] = *(const float4*)&Ws1[i];
    for (int i = threadIdx.x * 4; i < 64 * 64; i += 256 * 4)
        *(float4*)&sW2[i] = *(const float4*)&Ws2[i];
    int ul = threadIdx.x >> 6;
    int c = threadIdx.x & 63;
    for (int base = blockIdx.x * 4; base < nu; base += gridDim.x * 4) {
        int u = base + ul;
        __syncthreads();
        if (u < nu) {
            int node = users[u];
            *(float2*)&sU[ul][c * 2] = *(const float2*)&h[(size_t)node * DIM + c * 2];
        }
        __syncthreads();
        float t = 0.f;
        if (u < nu) {
            float acc = bs1[c];
#pragma unroll 8
            for (int k = 0; k < DIM; ++k) acc = fmaf(sU[ul][k], sW1[k * 64 + c], acc);
            t = tanhf(acc);
        }
        sT[ul][c] = t;
        __syncthreads();
        if (u < nu) {
            float acc = bs2[c];
#pragma unroll 8
            for (int k = 0; k < 64; ++k) acc = fmaf(sT[ul][k], sW2[k * 64 + c], acc);
            R[(size_t)u * 64 + c] = acc;
        }
    }
}

extern "C" void kernel_launch(void* const* d_in, const int* in_sizes, int n_in,
                              void* d_out, int out_size, void* d_ws, size_t ws_size,
                              hipStream_t stream) {
    const float* features = (const float*)d_in[0];
    const float* W0  = (const float*)d_in[1];
    const float* b0  = (const float*)d_in[2];
    const float* W1  = (const float*)d_in[3];
    const float* b1  = (const float*)d_in[4];
    const float* Ws1 = (const float*)d_in[5];
    const float* bs1 = (const float*)d_in[6];
    const float* Ws2 = (const float*)d_in[7];
    const float* bs2 = (const float*)d_in[8];
    const int* src   = (const int*)d_in[9];
    const int* dst   = (const int*)d_in[10];
    const int* users = (const int*)d_in[11];

    float* R = (float*)d_out;
    float* H = (float*)d_out + (size_t)NU * 64;

    char* ws = (char*)d_ws;
    // hist buffers overlay hsA: dead before matmul1 writes hsA
    __half* hsA  = (__half*)(ws + 0);                      // 12.8 MB
    unsigned int* histD = (unsigned int*)(ws + 0);         //  6.4 MB (128 x 50000B)
    unsigned int* histS = (unsigned int*)(ws + 6400000);   //  6.4 MB
    int* csc     = (int*)(ws + 12800000);                  //  6.4 MB
    unsigned char* rel8 = (unsigned char*)(ws + 19200000); //  6.4 MB
    int*   din   = (int*)  (ws + 25600000);
    float* cs    = (float*)(ws + 25800000);
    float* cd    = (float*)(ws + 26000000);
    int*   offs  = (int*)  (ws + 26200000);
    int*   partials = (int*)(ws + 26400000);
    int*   bases    = (int*)(ws + 26401024);               // end ~26.5 MB

    k_hist<<<2 * NB, 512, 0, stream>>>((const int4*)src, (const int4*)dst, histD, histS);
    k_reduce_norms<<<NSC, 256, 0, stream>>>(histD, histS, din, cs, cd, partials);
    k_scan2<<<1, 64, 0, stream>>>(partials, bases);
    k_scan3<<<NSC, 256, 0, stream>>>(din, bases, offs);
    k_blockbase<<<(NN + 255) / 256, 256, 0, stream>>>(histD, rel8);
    k_scatter2<<<NB, 512, 0, stream>>>((const int4*)src, (const int4*)dst, offs, rel8, csc);

    // layer 1
    k_matmul_cs<<<1024, 256, 0, stream>>>(features, W0, cs, hsA, NN);
    k_aggregate<<<12500, 256, 0, stream>>>(hsA, csc, offs, din, cd, b0, H);

    // layer 2
    k_matmul_cs<<<1024, 256, 0, stream>>>(H, W1, cs, hsA, NN);
    k_aggregate<<<12500, 256, 0, stream>>>(hsA, csc, offs, din, cd, b1, H);

    // SR head
    k_sr_head<<<2500, 256, 0, stream>>>(H, users, Ws1, bs1, Ws2, bs2, R, NU);
}

// Round 12
// 305.235 us; speedup vs baseline: 1.7338x; 1.0133x over previous
//
#include <hip/hip_runtime.h>
#include <hip/hip_bf16.h>
#include <hip/hip_fp16.h>

#define NN 50000
#define NE 1600000
#define DIM 128
#define NU 10000
#define NB 256           // histogram/scatter chunks
#define SLICE_W 12500    // NN/4 packed-uint8 words per slice
#define NE4 (NE / 4)
#define CHUNK4 ((NE4 + NB - 1) / NB)   // 1563 int4 per block (last block short)
#define NSC 49           // scan blocks: ceil(NN/1024)

// Fused per-chunk packed-uint8 histograms: blocks [0,NB) -> dst, [NB,2NB) -> src
__global__ __launch_bounds__(512) void k_hist(const int4* __restrict__ src4,
                                              const int4* __restrict__ dst4,
                                              unsigned int* __restrict__ histD,
                                              unsigned int* __restrict__ histS) {
    __shared__ unsigned int lh[SLICE_W];   // 50 KB
    for (int i = threadIdx.x; i < SLICE_W; i += 512) lh[i] = 0u;
    __syncthreads();
    int b = blockIdx.x & (NB - 1);
    const int4* idx4 = (blockIdx.x < NB) ? dst4 : src4;
    unsigned int* out = ((blockIdx.x < NB) ? histD : histS) + (size_t)b * SLICE_W;
    int beg = b * CHUNK4, end = min(beg + CHUNK4, NE4);
    for (int i = beg + threadIdx.x; i < end; i += 512) {
        int4 v = idx4[i];
        atomicAdd(&lh[v.x >> 2], 1u << ((v.x & 3) * 8));
        atomicAdd(&lh[v.y >> 2], 1u << ((v.y & 3) * 8));
        atomicAdd(&lh[v.z >> 2], 1u << ((v.z & 3) * 8));
        atomicAdd(&lh[v.w >> 2], 1u << ((v.w & 3) * 8));
    }
    __syncthreads();
    for (int i = threadIdx.x; i < SLICE_W; i += 512) out[i] = lh[i];
}

// Sum NB slices per node; emit din, cs, cd, per-block degree partials
__global__ __launch_bounds__(256) void k_reduce_norms(const unsigned int* __restrict__ histD,
                                                      const unsigned int* __restrict__ histS,
                                                      int* __restrict__ din,
                                                      float* __restrict__ cs, float* __restrict__ cd,
                                                      int* __restrict__ partials) {
    __shared__ int red[256];
    int wi = blockIdx.x * blockDim.x + threadIdx.x;
    unsigned int d0 = 0, d1 = 0, d2 = 0, d3 = 0, s0 = 0, s1 = 0, s2 = 0, s3 = 0;
    if (wi < SLICE_W) {
        for (int b = 0; b < NB; ++b) {
            unsigned int wd = histD[(size_t)b * SLICE_W + wi];
            unsigned int ws = histS[(size_t)b * SLICE_W + wi];
            d0 += wd & 0xFFu; d1 += (wd >> 8) & 0xFFu; d2 += (wd >> 16) & 0xFFu; d3 += wd >> 24;
            s0 += ws & 0xFFu; s1 += (ws >> 8) & 0xFFu; s2 += (ws >> 16) & 0xFFu; s3 += ws >> 24;
        }
        int n = wi * 4;
        *(int4*)&din[n] = make_int4(d0, d1, d2, d3);
        float4 vcd, vcs;
        vcd.x = rsqrtf(fmaxf((float)d0, 1.f)); vcd.y = rsqrtf(fmaxf((float)d1, 1.f));
        vcd.z = rsqrtf(fmaxf((float)d2, 1.f)); vcd.w = rsqrtf(fmaxf((float)d3, 1.f));
        vcs.x = rsqrtf(fmaxf((float)s0, 1.f)); vcs.y = rsqrtf(fmaxf((float)s1, 1.f));
        vcs.z = rsqrtf(fmaxf((float)s2, 1.f)); vcs.w = rsqrtf(fmaxf((float)s3, 1.f));
        *(float4*)&cd[n] = vcd;
        *(float4*)&cs[n] = vcs;
    }
    red[threadIdx.x] = (int)(d0 + d1 + d2 + d3);
    __syncthreads();
    for (int off = 128; off > 0; off >>= 1) {
        if (threadIdx.x < off) red[threadIdx.x] += red[threadIdx.x + off];
        __syncthreads();
    }
    if (threadIdx.x == 0) partials[blockIdx.x] = red[0];
}

__global__ __launch_bounds__(64) void k_scan2(const int* __restrict__ partials,
                                              int* __restrict__ bases) {
    int lane = threadIdx.x;
    int v = (lane < NSC) ? partials[lane] : 0;
    int s = v;
    for (int off = 1; off < 64; off <<= 1) {
        int n = __shfl_up(s, off);
        if (lane >= off) s += n;
    }
    if (lane < NSC) bases[lane] = s - v;
}

__global__ __launch_bounds__(256) void k_scan3(const int* __restrict__ din,
                                               const int* __restrict__ bases,
                                               int* __restrict__ offs) {
    __shared__ int part[256];
    int t = threadIdx.x;
    int n0 = blockIdx.x * 1024 + t * 4;
    int4 d = make_int4(0, 0, 0, 0);
    if (n0 < NN) d = *(const int4*)&din[n0];
    int tsum = d.x + d.y + d.z + d.w;
    part[t] = tsum;
    __syncthreads();
    for (int off = 1; off < 256; off <<= 1) {
        int v = (t >= off) ? part[t - off] : 0;
        __syncthreads();
        part[t] += v;
        __syncthreads();
    }
    if (n0 < NN) {
        int o = bases[blockIdx.x] + part[t] - tsum;
        *(int4*)&offs[n0] = make_int4(o, o + d.x, o + d.x + d.y, o + d.x + d.y + d.z);
    }
}

// rel8[b][n] = sum over b' < b of histD[b'][n]  (<= deg_in, fits uint8)
__global__ __launch_bounds__(256) void k_blockbase(const unsigned int* __restrict__ histD,
                                                   unsigned char* __restrict__ rel8) {
    int n = blockIdx.x * blockDim.x + threadIdx.x;
    if (n >= NN) return;
    int wi = n >> 2, sh = (n & 3) * 8;
    unsigned int run = 0;
    for (int b = 0; b < NB; ++b) {
        rel8[(size_t)b * NN + n] = (unsigned char)run;
        run += (histD[(size_t)b * SLICE_W + wi] >> sh) & 0xFFu;
    }
}

// Atomic-free CSC scatter: local position from LDS packed-byte cursor
__global__ __launch_bounds__(512) void k_scatter2(const int4* __restrict__ src4,
                                                  const int4* __restrict__ dst4,
                                                  const int* __restrict__ offs,
                                                  const unsigned char* __restrict__ rel8,
                                                  int* __restrict__ csc) {
    __shared__ unsigned int lc[SLICE_W];   // 50 KB
    for (int i = threadIdx.x; i < SLICE_W; i += 512) lc[i] = 0u;
    __syncthreads();
    int b = blockIdx.x;
    const unsigned char* rel = rel8 + (size_t)b * NN;
    int beg = b * CHUNK4, end = min(beg + CHUNK4, NE4);
    for (int i = beg + threadIdx.x; i < end; i += 512) {
        int4 s = src4[i];
        int4 d = dst4[i];
#pragma unroll
        for (int j = 0; j < 4; ++j) {
            int dd = (j == 0) ? d.x : (j == 1) ? d.y : (j == 2) ? d.z : d.w;
            int ss = (j == 0) ? s.x : (j == 1) ? s.y : (j == 2) ? s.z : s.w;
            int sh = (dd & 3) * 8;
            unsigned int old = atomicAdd(&lc[dd >> 2], 1u << sh);
            int local = (old >> sh) & 0xFF;
            csc[offs[dd] + rel[dd] + local] = ss;
        }
    }
}

// Y[r][:] = fp16((X[r][:] @ W) * cs[r]) ; 4 rows per wave (R4-benched version, no spills)
__global__ __launch_bounds__(256) void k_matmul_cs(const float* __restrict__ X,
                                                   const float* __restrict__ W,
                                                   const float* __restrict__ cs,
                                                   __half* __restrict__ Y, int nrows) {
    __shared__ float sW[DIM * DIM];   // 64 KB
    __shared__ float sX[16][DIM];     //  8 KB
    for (int i = threadIdx.x * 4; i < DIM * DIM; i += 256 * 4)
        *(float4*)&sW[i] = *(const float4*)&W[i];
    int rl = threadIdx.x >> 6;
    int c = (threadIdx.x & 63) * 2;
    int ngroups = (nrows + 15) >> 4;
    for (int g = blockIdx.x; g < ngroups; g += gridDim.x) {
        __syncthreads();
        {
            int row = threadIdx.x >> 4;
            int col = (threadIdx.x & 15) * 8;
            int rr = min(g * 16 + row, nrows - 1);
            const float* xp = X + (size_t)rr * DIM + col;
            *(float4*)&sX[row][col] = *(const float4*)xp;
            *(float4*)&sX[row][col + 4] = *(const float4*)(xp + 4);
        }
        __syncthreads();
        float acc[4][2] = {};
#pragma unroll 4
        for (int k = 0; k < DIM; ++k) {
            float2 w = *(const float2*)&sW[k * DIM + c];
            float x0 = sX[rl * 4 + 0][k];
            float x1 = sX[rl * 4 + 1][k];
            float x2 = sX[rl * 4 + 2][k];
            float x3 = sX[rl * 4 + 3][k];
            acc[0][0] = fmaf(x0, w.x, acc[0][0]); acc[0][1] = fmaf(x0, w.y, acc[0][1]);
            acc[1][0] = fmaf(x1, w.x, acc[1][0]); acc[1][1] = fmaf(x1, w.y, acc[1][1]);
            acc[2][0] = fmaf(x2, w.x, acc[2][0]); acc[2][1] = fmaf(x2, w.y, acc[2][1]);
            acc[3][0] = fmaf(x3, w.x, acc[3][0]); acc[3][1] = fmaf(x3, w.y, acc[3][1]);
        }
#pragma unroll
        for (int j = 0; j < 4; ++j) {
            int r = g * 16 + rl * 4 + j;
            if (r < nrows) {
                float s = cs[r];
                __half2 hv = __float22half2_rn(make_float2(acc[j][0] * s, acc[j][1] * s));
                *(__half2*)&Y[(size_t)r * DIM + c] = hv;
            }
        }
    }
}

// Full-row aggregate, 8-deep edge unroll: 32 lanes x 8B cover the 256B row,
// wave-halves take even/odd edge slots, each half keeps 8 gathers in flight.
__global__ __launch_bounds__(256) void k_aggregate(const __half* __restrict__ hs,
                                                   const int* __restrict__ csc,
                                                   const int* __restrict__ offs,
                                                   const int* __restrict__ din,
                                                   const float* __restrict__ cd,
                                                   const float* __restrict__ bias,
                                                   float* __restrict__ out) {
    int wid = threadIdx.x >> 6;
    int lane = threadIdx.x & 63;
    int h = lane >> 5;        // edge-slot parity
    int l = lane & 31;        // dim group: dims l*4 .. l*4+3
    int d = blockIdx.x * 4 + wid;   // NN % 4 == 0
    int beg = offs[d];
    int end = beg + din[d];
    const __half* base = hs + l * 4;
    float a0 = 0.f, a1 = 0.f, a2 = 0.f, a3 = 0.f;
    float b0 = 0.f, b1 = 0.f, b2 = 0.f, b3 = 0.f;
    float c0 = 0.f, c1 = 0.f, c2 = 0.f, c3 = 0.f;
    float e0 = 0.f, e1 = 0.f, e2 = 0.f, e3 = 0.f;
    int i = beg + h;
    // 8-deep: slots i, i+2, ..., i+14
    for (; i + 14 < end; i += 16) {
        int sI[8];
#pragma unroll
        for (int j = 0; j < 8; ++j) sI[j] = csc[i + 2 * j];
        short4 vI[8];
#pragma unroll
        for (int j = 0; j < 8; ++j) vI[j] = *(const short4*)(base + (size_t)sI[j] * DIM);
#pragma unroll
        for (int j = 0; j < 8; j += 4) {
            float2 x0 = __half22float2(*(const __half2*)&vI[j].x);
            float2 x1 = __half22float2(*(const __half2*)&vI[j].z);
            float2 y0 = __half22float2(*(const __half2*)&vI[j + 1].x);
            float2 y1 = __half22float2(*(const __half2*)&vI[j + 1].z);
            float2 z0 = __half22float2(*(const __half2*)&vI[j + 2].x);
            float2 z1 = __half22float2(*(const __half2*)&vI[j + 2].z);
            float2 w0 = __half22float2(*(const __half2*)&vI[j + 3].x);
            float2 w1 = __half22float2(*(const __half2*)&vI[j + 3].z);
            a0 += x0.x; a1 += x0.y; a2 += x1.x; a3 += x1.y;
            b0 += y0.x; b1 += y0.y; b2 += y1.x; b3 += y1.y;
            c0 += z0.x; c1 += z0.y; c2 += z1.x; c3 += z1.y;
            e0 += w0.x; e1 += w0.y; e2 += w1.x; e3 += w1.y;
        }
    }
    // 4-deep remainder
    for (; i + 6 < end; i += 8) {
        int s0 = csc[i], s1 = csc[i + 2], s2 = csc[i + 4], s3 = csc[i + 6];
        short4 v0 = *(const short4*)(base + (size_t)s0 * DIM);
        short4 v1 = *(const short4*)(base + (size_t)s1 * DIM);
        short4 v2 = *(const short4*)(base + (size_t)s2 * DIM);
        short4 v3 = *(const short4*)(base + (size_t)s3 * DIM);
        float2 x0 = __half22float2(*(const __half2*)&v0.x);
        float2 x1 = __half22float2(*(const __half2*)&v0.z);
        float2 y0 = __half22float2(*(const __half2*)&v1.x);
        float2 y1 = __half22float2(*(const __half2*)&v1.z);
        float2 z0 = __half22float2(*(const __half2*)&v2.x);
        float2 z1 = __half22float2(*(const __half2*)&v2.z);
        float2 w0 = __half22float2(*(const __half2*)&v3.x);
        float2 w1 = __half22float2(*(const __half2*)&v3.z);
        a0 += x0.x; a1 += x0.y; a2 += x1.x; a3 += x1.y;
        b0 += y0.x; b1 += y0.y; b2 += y1.x; b3 += y1.y;
        c0 += z0.x; c1 += z0.y; c2 += z1.x; c3 += z1.y;
        e0 += w0.x; e1 += w0.y; e2 += w1.x; e3 += w1.y;
    }
    for (; i < end; i += 2) {
        int s = csc[i];
        short4 v = *(const short4*)(base + (size_t)s * DIM);
        float2 x0 = __half22float2(*(const __half2*)&v.x);
        float2 x1 = __half22float2(*(const __half2*)&v.z);
        a0 += x0.x; a1 += x0.y; a2 += x1.x; a3 += x1.y;
    }
    a0 += b0 + c0 + e0; a1 += b1 + c1 + e1;
    a2 += b2 + c2 + e2; a3 += b3 + c3 + e3;
    a0 += __shfl(a0, lane ^ 32);
    a1 += __shfl(a1, lane ^ 32);
    a2 += __shfl(a2, lane ^ 32);
    a3 += __shfl(a3, lane ^ 32);
    if (h == 0) {
        float c = cd[d];
        float4 bv = *(const float4*)&bias[l * 4];
        float4 o;
        o.x = fmaxf(fmaf(a0, c, bv.x), 0.f);
        o.y = fmaxf(fmaf(a1, c, bv.y), 0.f);
        o.z = fmaxf(fmaf(a2, c, bv.z), 0.f);
        o.w = fmaxf(fmaf(a3, c, bv.w), 0.f);
        *(float4*)&out[(size_t)d * DIM + l * 4] = o;
    }
}

// R[u][:] = tanh(h[users[u]] @ Ws1 + bs1) @ Ws2 + bs2
__global__ __launch_bounds__(256) void k_sr_head(const float* __restrict__ h,
                                                 const int* __restrict__ users,
                                                 const float* __restrict__ Ws1,
                                                 const float* __restrict__ bs1,
                                                 const float* __restrict__ Ws2,
                                                 const float* __restrict__ bs2,
                                                 float* __restrict__ R, int nu) {
    __shared__ float sW1[DIM * 64];
    __shared__ float sW2[64 * 64];
    __shared__ float sU[4][DIM];
    __shared__ float sT[4][64];
    for (int i = threadIdx.x * 4; i < DIM * 64; i += 256 * 4)
        *(float4*)&sW1[i] = *(const float4*)&Ws1[i];
    for (int i = threadIdx.x * 4; i < 64 * 64; i += 256 * 4)
        *(float4*)&sW2[i] = *(const float4*)&Ws2[i];
    int ul = threadIdx.x >> 6;
    int c = threadIdx.x & 63;
    for (int base = blockIdx.x * 4; base < nu; base += gridDim.x * 4) {
        int u = base + ul;
        __syncthreads();
        if (u < nu) {
            int node = users[u];
            *(float2*)&sU[ul][c * 2] = *(const float2*)&h[(size_t)node * DIM + c * 2];
        }
        __syncthreads();
        float t = 0.f;
        if (u < nu) {
            float acc = bs1[c];
#pragma unroll 8
            for (int k = 0; k < DIM; ++k) acc = fmaf(sU[ul][k], sW1[k * 64 + c], acc);
            t = tanhf(acc);
        }
        sT[ul][c] = t;
        __syncthreads();
        if (u < nu) {
            float acc = bs2[c];
#pragma unroll 8
            for (int k = 0; k < 64; ++k) acc = fmaf(sT[ul][k], sW2[k * 64 + c], acc);
            R[(size_t)u * 64 + c] = acc;
        }
    }
}

extern "C" void kernel_launch(void* const* d_in, const int* in_sizes, int n_in,
                              void* d_out, int out_size, void* d_ws, size_t ws_size,
                              hipStream_t stream) {
    const float* features = (const float*)d_in[0];
    const float* W0  = (const float*)d_in[1];
    const float* b0  = (const float*)d_in[2];
    const float* W1  = (const float*)d_in[3];
    const float* b1  = (const float*)d_in[4];
    const float* Ws1 = (const float*)d_in[5];
    const float* bs1 = (const float*)d_in[6];
    const float* Ws2 = (const float*)d_in[7];
    const float* bs2 = (const float*)d_in[8];
    const int* src   = (const int*)d_in[9];
    const int* dst   = (const int*)d_in[10];
    const int* users = (const int*)d_in[11];

    float* R = (float*)d_out;
    float* H = (float*)d_out + (size_t)NU * 64;

    char* ws = (char*)d_ws;
    // Overlays (all temporally disjoint, launches are stream-ordered):
    //   histD (0..12.8M)   dead after k_blockbase; hsA written later by matmul1
    //   histS (12.8..25.6M) dead after k_reduce_norms; rel8 written by k_blockbase
    __half* hsA  = (__half*)(ws + 0);                      // 12.8 MB
    unsigned int* histD = (unsigned int*)(ws + 0);         // 12.8 MB (256 x 50000B)
    unsigned int* histS = (unsigned int*)(ws + 12800000);  // 12.8 MB
    unsigned char* rel8 = (unsigned char*)(ws + 12800000); // 12.8 MB (overlays dead histS)
    int* csc     = (int*)(ws + 25600000);                  //  6.4 MB
    int*   din   = (int*)  (ws + 32000000);
    float* cs    = (float*)(ws + 32200000);
    float* cd    = (float*)(ws + 32400000);
    int*   offs  = (int*)  (ws + 32600000);
    int*   partials = (int*)(ws + 32800000);
    int*   bases    = (int*)(ws + 32801024);               // end ~32.81 MB

    k_hist<<<2 * NB, 512, 0, stream>>>((const int4*)src, (const int4*)dst, histD, histS);
    k_reduce_norms<<<NSC, 256, 0, stream>>>(histD, histS, din, cs, cd, partials);
    k_scan2<<<1, 64, 0, stream>>>(partials, bases);
    k_scan3<<<NSC, 256, 0, stream>>>(din, bases, offs);
    k_blockbase<<<(NN + 255) / 256, 256, 0, stream>>>(histD, rel8);
    k_scatter2<<<NB, 512, 0, stream>>>((const int4*)src, (const int4*)dst, offs, rel8, csc);

    // layer 1
    k_matmul_cs<<<512, 256, 0, stream>>>(features, W0, cs, hsA, NN);
    k_aggregate<<<12500, 256, 0, stream>>>(hsA, csc, offs, din, cd, b0, H);

    // layer 2
    k_matmul_cs<<<512, 256, 0, stream>>>(H, W1, cs, hsA, NN);
    k_aggregate<<<12500, 256, 0, stream>>>(hsA, csc, offs, din, cd, b1, H);

    // SR head
    k_sr_head<<<625, 256, 0, stream>>>(H, users, Ws1, bs1, Ws2, bs2, R, NU);
}

// Round 13
// 294.646 us; speedup vs baseline: 1.7961x; 1.0359x over previous
//
#include <hip/hip_runtime.h>
#include <hip/hip_bf16.h>
#include <hip/hip_fp16.h>

#define NN 50000
#define NE 1600000
#define DIM 128
#define NU 10000
#define NB 256           // histogram/scatter chunks
#define SLICE_W 12500    // NN/4 packed-uint8 words per slice
#define NE4 (NE / 4)
#define CHUNK4 ((NE4 + NB - 1) / NB)   // int4 per block
#define NSC 49           // scan blocks: ceil(NN/1024)

// Fused per-chunk packed-uint8 histograms: blocks [0,NB) -> dst, [NB,2NB) -> src
__global__ __launch_bounds__(512) void k_hist(const int4* __restrict__ src4,
                                              const int4* __restrict__ dst4,
                                              unsigned int* __restrict__ histD,
                                              unsigned int* __restrict__ histS) {
    __shared__ unsigned int lh[SLICE_W];   // 50 KB
    for (int i = threadIdx.x; i < SLICE_W; i += 512) lh[i] = 0u;
    __syncthreads();
    int b = blockIdx.x & (NB - 1);
    const int4* idx4 = (blockIdx.x < NB) ? dst4 : src4;
    unsigned int* out = ((blockIdx.x < NB) ? histD : histS) + (size_t)b * SLICE_W;
    int beg = b * CHUNK4, end = min(beg + CHUNK4, NE4);
    for (int i = beg + threadIdx.x; i < end; i += 512) {
        int4 v = idx4[i];
        atomicAdd(&lh[v.x >> 2], 1u << ((v.x & 3) * 8));
        atomicAdd(&lh[v.y >> 2], 1u << ((v.y & 3) * 8));
        atomicAdd(&lh[v.z >> 2], 1u << ((v.z & 3) * 8));
        atomicAdd(&lh[v.w >> 2], 1u << ((v.w & 3) * 8));
    }
    __syncthreads();
    for (int i = threadIdx.x; i < SLICE_W; i += 512) out[i] = lh[i];
}

// Sum NB slices per node; emit din, cs, cd, per-block degree partials
__global__ __launch_bounds__(256) void k_reduce_norms(const unsigned int* __restrict__ histD,
                                                      const unsigned int* __restrict__ histS,
                                                      int* __restrict__ din,
                                                      float* __restrict__ cs, float* __restrict__ cd,
                                                      int* __restrict__ partials) {
    __shared__ int red[256];
    int wi = blockIdx.x * blockDim.x + threadIdx.x;
    unsigned int d0 = 0, d1 = 0, d2 = 0, d3 = 0, s0 = 0, s1 = 0, s2 = 0, s3 = 0;
    if (wi < SLICE_W) {
        for (int b = 0; b < NB; ++b) {
            unsigned int wd = histD[(size_t)b * SLICE_W + wi];
            unsigned int ws = histS[(size_t)b * SLICE_W + wi];
            d0 += wd & 0xFFu; d1 += (wd >> 8) & 0xFFu; d2 += (wd >> 16) & 0xFFu; d3 += wd >> 24;
            s0 += ws & 0xFFu; s1 += (ws >> 8) & 0xFFu; s2 += (ws >> 16) & 0xFFu; s3 += ws >> 24;
        }
        int n = wi * 4;
        *(int4*)&din[n] = make_int4(d0, d1, d2, d3);
        float4 vcd, vcs;
        vcd.x = rsqrtf(fmaxf((float)d0, 1.f)); vcd.y = rsqrtf(fmaxf((float)d1, 1.f));
        vcd.z = rsqrtf(fmaxf((float)d2, 1.f)); vcd.w = rsqrtf(fmaxf((float)d3, 1.f));
        vcs.x = rsqrtf(fmaxf((float)s0, 1.f)); vcs.y = rsqrtf(fmaxf((float)s1, 1.f));
        vcs.z = rsqrtf(fmaxf((float)s2, 1.f)); vcs.w = rsqrtf(fmaxf((float)s3, 1.f));
        *(float4*)&cd[n] = vcd;
        *(float4*)&cs[n] = vcs;
    }
    red[threadIdx.x] = (int)(d0 + d1 + d2 + d3);
    __syncthreads();
    for (int off = 128; off > 0; off >>= 1) {
        if (threadIdx.x < off) red[threadIdx.x] += red[threadIdx.x + off];
        __syncthreads();
    }
    if (threadIdx.x == 0) partials[blockIdx.x] = red[0];
}

__global__ __launch_bounds__(64) void k_scan2(const int* __restrict__ partials,
                                              int* __restrict__ bases) {
    int lane = threadIdx.x;
    int v = (lane < NSC) ? partials[lane] : 0;
    int s = v;
    for (int off = 1; off < 64; off <<= 1) {
        int n = __shfl_up(s, off);
        if (lane >= off) s += n;
    }
    if (lane < NSC) bases[lane] = s - v;
}

__global__ __launch_bounds__(256) void k_scan3(const int* __restrict__ din,
                                               const int* __restrict__ bases,
                                               int* __restrict__ offs) {
    __shared__ int part[256];
    int t = threadIdx.x;
    int n0 = blockIdx.x * 1024 + t * 4;
    int4 d = make_int4(0, 0, 0, 0);
    if (n0 < NN) d = *(const int4*)&din[n0];
    int tsum = d.x + d.y + d.z + d.w;
    part[t] = tsum;
    __syncthreads();
    for (int off = 1; off < 256; off <<= 1) {
        int v = (t >= off) ? part[t - off] : 0;
        __syncthreads();
        part[t] += v;
        __syncthreads();
    }
    if (n0 < NN) {
        int o = bases[blockIdx.x] + part[t] - tsum;
        *(int4*)&offs[n0] = make_int4(o, o + d.x, o + d.x + d.y, o + d.x + d.y + d.z);
    }
}

// rel8[b][n] = sum over b' < b of histD[b'][n]  (<= deg_in, fits uint8)
__global__ __launch_bounds__(256) void k_blockbase(const unsigned int* __restrict__ histD,
                                                   unsigned char* __restrict__ rel8) {
    int n = blockIdx.x * blockDim.x + threadIdx.x;
    if (n >= NN) return;
    int wi = n >> 2, sh = (n & 3) * 8;
    unsigned int run = 0;
    for (int b = 0; b < NB; ++b) {
        rel8[(size_t)b * NN + n] = (unsigned char)run;
        run += (histD[(size_t)b * SLICE_W + wi] >> sh) & 0xFFu;
    }
}

// Atomic-free CSC scatter: local position from LDS packed-byte cursor
__global__ __launch_bounds__(512) void k_scatter2(const int4* __restrict__ src4,
                                                  const int4* __restrict__ dst4,
                                                  const int* __restrict__ offs,
                                                  const unsigned char* __restrict__ rel8,
                                                  int* __restrict__ csc) {
    __shared__ unsigned int lc[SLICE_W];   // 50 KB
    for (int i = threadIdx.x; i < SLICE_W; i += 512) lc[i] = 0u;
    __syncthreads();
    int b = blockIdx.x;
    const unsigned char* rel = rel8 + (size_t)b * NN;
    int beg = b * CHUNK4, end = min(beg + CHUNK4, NE4);
    for (int i = beg + threadIdx.x; i < end; i += 512) {
        int4 s = src4[i];
        int4 d = dst4[i];
#pragma unroll
        for (int j = 0; j < 4; ++j) {
            int dd = (j == 0) ? d.x : (j == 1) ? d.y : (j == 2) ? d.z : d.w;
            int ss = (j == 0) ? s.x : (j == 1) ? s.y : (j == 2) ? s.z : s.w;
            int sh = (dd & 3) * 8;
            unsigned int old = atomicAdd(&lc[dd >> 2], 1u << sh);
            int local = (old >> sh) & 0xFF;
            csc[offs[dd] + rel[dd] + local] = ss;
        }
    }
}

// Y[r][:] = fp16((X[r][:] @ W) * cs[r]) ; W staged fp16 in LDS (40KB total -> 4 blocks/CU)
__global__ __launch_bounds__(256) void k_matmul_cs(const float* __restrict__ X,
                                                   const float* __restrict__ W,
                                                   const float* __restrict__ cs,
                                                   __half* __restrict__ Y, int nrows) {
    __shared__ __half sW[DIM * DIM];  // 32 KB
    __shared__ float sX[16][DIM];     //  8 KB
    for (int i = threadIdx.x * 4; i < DIM * DIM; i += 256 * 4) {
        float4 w4 = *(const float4*)&W[i];
        *(__half2*)&sW[i]     = __float22half2_rn(make_float2(w4.x, w4.y));
        *(__half2*)&sW[i + 2] = __float22half2_rn(make_float2(w4.z, w4.w));
    }
    int rl = threadIdx.x >> 6;
    int c = (threadIdx.x & 63) * 2;
    int ngroups = (nrows + 15) >> 4;
    for (int g = blockIdx.x; g < ngroups; g += gridDim.x) {
        __syncthreads();
        {
            int row = threadIdx.x >> 4;
            int col = (threadIdx.x & 15) * 8;
            int rr = min(g * 16 + row, nrows - 1);
            const float* xp = X + (size_t)rr * DIM + col;
            *(float4*)&sX[row][col] = *(const float4*)xp;
            *(float4*)&sX[row][col + 4] = *(const float4*)(xp + 4);
        }
        __syncthreads();
        float acc[4][2] = {};
#pragma unroll 4
        for (int k = 0; k < DIM; ++k) {
            float2 w = __half22float2(*(const __half2*)&sW[k * DIM + c]);
            float x0 = sX[rl * 4 + 0][k];
            float x1 = sX[rl * 4 + 1][k];
            float x2 = sX[rl * 4 + 2][k];
            float x3 = sX[rl * 4 + 3][k];
            acc[0][0] = fmaf(x0, w.x, acc[0][0]); acc[0][1] = fmaf(x0, w.y, acc[0][1]);
            acc[1][0] = fmaf(x1, w.x, acc[1][0]); acc[1][1] = fmaf(x1, w.y, acc[1][1]);
            acc[2][0] = fmaf(x2, w.x, acc[2][0]); acc[2][1] = fmaf(x2, w.y, acc[2][1]);
            acc[3][0] = fmaf(x3, w.x, acc[3][0]); acc[3][1] = fmaf(x3, w.y, acc[3][1]);
        }
#pragma unroll
        for (int j = 0; j < 4; ++j) {
            int r = g * 16 + rl * 4 + j;
            if (r < nrows) {
                float s = cs[r];
                __half2 hv = __float22half2_rn(make_float2(acc[j][0] * s, acc[j][1] * s));
                *(__half2*)&Y[(size_t)r * DIM + c] = hv;
            }
        }
    }
}

// Full-row aggregate, 8-deep edge unroll: 32 lanes x 8B cover the 256B row,
// wave-halves take even/odd edge slots, each half keeps 8 gathers in flight.
__global__ __launch_bounds__(256) void k_aggregate(const __half* __restrict__ hs,
                                                   const int* __restrict__ csc,
                                                   const int* __restrict__ offs,
                                                   const int* __restrict__ din,
                                                   const float* __restrict__ cd,
                                                   const float* __restrict__ bias,
                                                   float* __restrict__ out) {
    int wid = threadIdx.x >> 6;
    int lane = threadIdx.x & 63;
    int h = lane >> 5;        // edge-slot parity
    int l = lane & 31;        // dim group: dims l*4 .. l*4+3
    int d = blockIdx.x * 4 + wid;   // NN % 4 == 0
    int beg = offs[d];
    int end = beg + din[d];
    const __half* base = hs + l * 4;
    float a0 = 0.f, a1 = 0.f, a2 = 0.f, a3 = 0.f;
    float b0 = 0.f, b1 = 0.f, b2 = 0.f, b3 = 0.f;
    float c0 = 0.f, c1 = 0.f, c2 = 0.f, c3 = 0.f;
    float e0 = 0.f, e1 = 0.f, e2 = 0.f, e3 = 0.f;
    int i = beg + h;
    for (; i + 14 < end; i += 16) {
        int sI[8];
#pragma unroll
        for (int j = 0; j < 8; ++j) sI[j] = csc[i + 2 * j];
        short4 vI[8];
#pragma unroll
        for (int j = 0; j < 8; ++j) vI[j] = *(const short4*)(base + (size_t)sI[j] * DIM);
#pragma unroll
        for (int j = 0; j < 8; j += 4) {
            float2 x0 = __half22float2(*(const __half2*)&vI[j].x);
            float2 x1 = __half22float2(*(const __half2*)&vI[j].z);
            float2 y0 = __half22float2(*(const __half2*)&vI[j + 1].x);
            float2 y1 = __half22float2(*(const __half2*)&vI[j + 1].z);
            float2 z0 = __half22float2(*(const __half2*)&vI[j + 2].x);
            float2 z1 = __half22float2(*(const __half2*)&vI[j + 2].z);
            float2 w0 = __half22float2(*(const __half2*)&vI[j + 3].x);
            float2 w1 = __half22float2(*(const __half2*)&vI[j + 3].z);
            a0 += x0.x; a1 += x0.y; a2 += x1.x; a3 += x1.y;
            b0 += y0.x; b1 += y0.y; b2 += y1.x; b3 += y1.y;
            c0 += z0.x; c1 += z0.y; c2 += z1.x; c3 += z1.y;
            e0 += w0.x; e1 += w0.y; e2 += w1.x; e3 += w1.y;
        }
    }
    for (; i + 6 < end; i += 8) {
        int s0 = csc[i], s1 = csc[i + 2], s2 = csc[i + 4], s3 = csc[i + 6];
        short4 v0 = *(const short4*)(base + (size_t)s0 * DIM);
        short4 v1 = *(const short4*)(base + (size_t)s1 * DIM);
        short4 v2 = *(const short4*)(base + (size_t)s2 * DIM);
        short4 v3 = *(const short4*)(base + (size_t)s3 * DIM);
        float2 x0 = __half22float2(*(const __half2*)&v0.x);
        float2 x1 = __half22float2(*(const __half2*)&v0.z);
        float2 y0 = __half22float2(*(const __half2*)&v1.x);
        float2 y1 = __half22float2(*(const __half2*)&v1.z);
        float2 z0 = __half22float2(*(const __half2*)&v2.x);
        float2 z1 = __half22float2(*(const __half2*)&v2.z);
        float2 w0 = __half22float2(*(const __half2*)&v3.x);
        float2 w1 = __half22float2(*(const __half2*)&v3.z);
        a0 += x0.x; a1 += x0.y; a2 += x1.x; a3 += x1.y;
        b0 += y0.x; b1 += y0.y; b2 += y1.x; b3 += y1.y;
        c0 += z0.x; c1 += z0.y; c2 += z1.x; c3 += z1.y;
        e0 += w0.x; e1 += w0.y; e2 += w1.x; e3 += w1.y;
    }
    for (; i < end; i += 2) {
        int s = csc[i];
        short4 v = *(const short4*)(base + (size_t)s * DIM);
        float2 x0 = __half22float2(*(const __half2*)&v.x);
        float2 x1 = __half22float2(*(const __half2*)&v.z);
        a0 += x0.x; a1 += x0.y; a2 += x1.x; a3 += x1.y;
    }
    a0 += b0 + c0 + e0; a1 += b1 + c1 + e1;
    a2 += b2 + c2 + e2; a3 += b3 + c3 + e3;
    a0 += __shfl(a0, lane ^ 32);
    a1 += __shfl(a1, lane ^ 32);
    a2 += __shfl(a2, lane ^ 32);
    a3 += __shfl(a3, lane ^ 32);
    if (h == 0) {
        float c = cd[d];
        float4 bv = *(const float4*)&bias[l * 4];
        float4 o;
        o.x = fmaxf(fmaf(a0, c, bv.x), 0.f);
        o.y = fmaxf(fmaf(a1, c, bv.y), 0.f);
        o.z = fmaxf(fmaf(a2, c, bv.z), 0.f);
        o.w = fmaxf(fmaf(a3, c, bv.w), 0.f);
        *(float4*)&out[(size_t)d * DIM + l * 4] = o;
    }
}

// R[u][:] = tanh(h[users[u]] @ Ws1 + bs1) @ Ws2 + bs2
__global__ __launch_bounds__(256) void k_sr_head(const float* __restrict__ h,
                                                 const int* __restrict__ users,
                                                 const float* __restrict__ Ws1,
                                                 const float* __restrict__ bs1,
                                                 const float* __restrict__ Ws2,
                                                 const float* __restrict__ bs2,
                                                 float* __restrict__ R, int nu) {
    __shared__ float sW1[DIM * 64];
    __shared__ float sW2[64 * 64];
    __shared__ float sU[4][DIM];
    __shared__ float sT[4][64];
    for (int i = threadIdx.x * 4; i < DIM * 64; i += 256 * 4)
        *(float4*)&sW1[i] = *(const float4*)&Ws1[i];
    for (int i = threadIdx.x * 4; i < 64 * 64; i += 256 * 4)
        *(float4*)&sW2[i] = *(const float4*)&Ws2[i];
    int ul = threadIdx.x >> 6;
    int c = threadIdx.x & 63;
    for (int base = blockIdx.x * 4; base < nu; base += gridDim.x * 4) {
        int u = base + ul;
        __syncthreads();
        if (u < nu) {
            int node = users[u];
            *(float2*)&sU[ul][c * 2] = *(const float2*)&h[(size_t)node * DIM + c * 2];
        }
        __syncthreads();
        float t = 0.f;
        if (u < nu) {
            float acc = bs1[c];
#pragma unroll 8
            for (int k = 0; k < DIM; ++k) acc = fmaf(sU[ul][k], sW1[k * 64 + c], acc);
            t = tanhf(acc);
        }
        sT[ul][c] = t;
        __syncthreads();
        if (u < nu) {
            float acc = bs2[c];
#pragma unroll 8
            for (int k = 0; k < 64; ++k) acc = fmaf(sT[ul][k], sW2[k * 64 + c], acc);
            R[(size_t)u * 64 + c] = acc;
        }
    }
}

extern "C" void kernel_launch(void* const* d_in, const int* in_sizes, int n_in,
                              void* d_out, int out_size, void* d_ws, size_t ws_size,
                              hipStream_t stream) {
    const float* features = (const float*)d_in[0];
    const float* W0  = (const float*)d_in[1];
    const float* b0  = (const float*)d_in[2];
    const float* W1  = (const float*)d_in[3];
    const float* b1  = (const float*)d_in[4];
    const float* Ws1 = (const float*)d_in[5];
    const float* bs1 = (const float*)d_in[6];
    const float* Ws2 = (const float*)d_in[7];
    const float* bs2 = (const float*)d_in[8];
    const int* src   = (const int*)d_in[9];
    const int* dst   = (const int*)d_in[10];
    const int* users = (const int*)d_in[11];

    float* R = (float*)d_out;
    float* H = (float*)d_out + (size_t)NU * 64;

    char* ws = (char*)d_ws;
    __half* hsA  = (__half*)(ws + 0);                      // 12.8 MB
    unsigned int* histD = (unsigned int*)(ws + 0);         // 12.8 MB (256 x 50000B)
    unsigned int* histS = (unsigned int*)(ws + 12800000);  // 12.8 MB
    unsigned char* rel8 = (unsigned char*)(ws + 12800000); // 12.8 MB (overlays dead histS)
    int* csc     = (int*)(ws + 25600000);                  //  6.4 MB
    int*   din   = (int*)  (ws + 32000000);
    float* cs    = (float*)(ws + 32200000);
    float* cd    = (float*)(ws + 32400000);
    int*   offs  = (int*)  (ws + 32600000);
    int*   partials = (int*)(ws + 32800000);
    int*   bases    = (int*)(ws + 32801024);

    k_hist<<<2 * NB, 512, 0, stream>>>((const int4*)src, (const int4*)dst, histD, histS);
    k_reduce_norms<<<NSC, 256, 0, stream>>>(histD, histS, din, cs, cd, partials);
    k_scan2<<<1, 64, 0, stream>>>(partials, bases);
    k_scan3<<<NSC, 256, 0, stream>>>(din, bases, offs);
    k_blockbase<<<(NN + 255) / 256, 256, 0, stream>>>(histD, rel8);
    k_scatter2<<<NB, 512, 0, stream>>>((const int4*)src, (const int4*)dst, offs, rel8, csc);

    // layer 1
    k_matmul_cs<<<1024, 256, 0, stream>>>(features, W0, cs, hsA, NN);
    k_aggregate<<<12500, 256, 0, stream>>>(hsA, csc, offs, din, cd, b0, H);

    // layer 2
    k_matmul_cs<<<1024, 256, 0, stream>>>(H, W1, cs, hsA, NN);
    k_aggregate<<<12500, 256, 0, stream>>>(hsA, csc, offs, din, cd, b1, H);

    // SR head
    k_sr_head<<<625, 256, 0, stream>>>(H, users, Ws1, bs1, Ws2, bs2, R, NU);
}